// Round 1
// baseline (267.002 us; speedup 1.0000x reference)
//
#include <hip/hip_runtime.h>
#include <hip/hip_bf16.h>

typedef __attribute__((ext_vector_type(4))) float floatx4;
typedef __attribute__((ext_vector_type(8))) short short8;

#define HIDDEN 256
#define NOUT 16384   // GDIM*GDIM*GROUPS = 64*64*4

__device__ __forceinline__ short bf16bits(float x) {
    __hip_bfloat16 h = __float2bfloat16(x);
    return __builtin_bit_cast(short, h);
}

// ---------------- Kernel A: w_dyn[M,16384] = bf16(qc[M,256] @ W_gen[256,16384] + b_gen) ----------------
// 64x64 tile per block, BK=32 (one MFMA K-step), 256 threads = 4 waves (each wave: 16 rows x 64 cols).
__global__ __launch_bounds__(256) void kA_gemm_w(
    const float* __restrict__ qc, const float* __restrict__ Wg,
    const float* __restrict__ bg, __hip_bfloat16* __restrict__ wdyn, int M)
{
    __shared__ short As[64 * 40];   // [m][k] bf16 bits, row pad 40 (80B rows, conflict-friendly)
    __shared__ short Bs[64 * 40];   // [n][k] transposed, same pad

    const int tid  = threadIdx.x;
    const int wave = tid >> 6, lane = tid & 63;
    const int lq   = lane & 15, quad = lane >> 4;
    const int n0   = blockIdx.x * 64;
    const int m0   = blockIdx.y * 64;

    floatx4 acc[4];
    #pragma unroll
    for (int t = 0; t < 4; ++t) acc[t] = (floatx4){0.f, 0.f, 0.f, 0.f};

    // A staging map: thread -> row = tid/4, 8 consecutive k at (tid%4)*8
    const int ar = tid >> 2;
    const int ac = (tid & 3) << 3;
    const int gm_a = m0 + ar;
    // B staging map: thread -> n = tid%64, 8 k's starting at (tid/64)*8 (column reads, coalesced per k)
    const int bn = tid & 63;
    const int bk = (tid >> 6) << 3;

    for (int k0 = 0; k0 < HIDDEN; k0 += 32) {
        // stage A (qc tile 64x32 -> bf16)
        float4 f0 = make_float4(0.f,0.f,0.f,0.f), f1 = make_float4(0.f,0.f,0.f,0.f);
        if (gm_a < M) {
            const float4* s = reinterpret_cast<const float4*>(qc + (size_t)gm_a * HIDDEN + k0 + ac);
            f0 = s[0]; f1 = s[1];
        }
        short8 av;
        av[0]=bf16bits(f0.x); av[1]=bf16bits(f0.y); av[2]=bf16bits(f0.z); av[3]=bf16bits(f0.w);
        av[4]=bf16bits(f1.x); av[5]=bf16bits(f1.y); av[6]=bf16bits(f1.z); av[7]=bf16bits(f1.w);
        *reinterpret_cast<short8*>(&As[ar*40 + ac]) = av;

        // stage B transposed (W_gen[k][n] -> Bs[n][k])
        {
            const float* bsrc = Wg + (size_t)(k0 + bk) * NOUT + n0 + bn;
            short8 bv;
            #pragma unroll
            for (int j = 0; j < 8; ++j) bv[j] = bf16bits(bsrc[(size_t)j * NOUT]);
            *reinterpret_cast<short8*>(&Bs[bn*40 + bk]) = bv;
        }
        __syncthreads();

        // compute: one a-frag per wave, 4 b-frags (4 N sub-tiles)
        short8 a = *reinterpret_cast<const short8*>(&As[(wave*16 + lq)*40 + quad*8]);
        #pragma unroll
        for (int t = 0; t < 4; ++t) {
            short8 b = *reinterpret_cast<const short8*>(&Bs[(t*16 + lq)*40 + quad*8]);
            acc[t] = __builtin_amdgcn_mfma_f32_16x16x32_bf16(a, b, acc[t], 0, 0, 0);
        }
        __syncthreads();
    }

    // epilogue: D layout col=lane&15, row=quad*4+reg; add bias, store bf16
    #pragma unroll
    for (int t = 0; t < 4; ++t) {
        const int gn = n0 + t*16 + lq;
        const float bv = bg[gn];
        #pragma unroll
        for (int r = 0; r < 4; ++r) {
            const int gm = m0 + wave*16 + quad*4 + r;
            if (gm < M) wdyn[(size_t)gm * NOUT + gn] = __float2bfloat16(acc[t][r] + bv);
        }
    }
}

// ---------------- Kernel B: per (b,n): mixed = grouped matmul(x, w^T); out = relu(LN(mixed)) ----------------
// 256 threads = 4 waves. wave -> mtile = wave&1 (16 p-rows), gpair = wave>>1 (2 groups).
__global__ __launch_bounds__(256) void kB_mix_ln(
    const float* __restrict__ x, const __hip_bfloat16* __restrict__ wdyn,
    const float* __restrict__ gamma, const float* __restrict__ beta,
    float* __restrict__ out)
{
    __shared__ short xs[32 * 264];   // x as bf16 bits, [p][264] (pad 8)
    __shared__ short ws2[256 * 72];  // w as bf16 bits, [c_out][72] (row = 64 d + pad 8)
    __shared__ float ms[32 * 260];   // mixed fp32, [p][260]
    __shared__ float gs[256], bs2[256];

    const int tid  = threadIdx.x;
    const int bnq  = blockIdx.x;
    const int wave = tid >> 6, lane = tid & 63;
    const int lq   = lane & 15, quad = lane >> 4;

    gs[tid]  = gamma[tid];
    bs2[tid] = beta[tid];

    // stage x -> bf16 LDS
    {
        const float4* xg = reinterpret_cast<const float4*>(x + (size_t)bnq * (32 * 256));
        #pragma unroll
        for (int i = 0; i < 4; ++i) {
            const int idx8 = tid + 256 * i;          // 8-float chunk, 1024 total
            const float4 f0 = xg[idx8*2], f1 = xg[idx8*2 + 1];
            const int lin = idx8 * 8;
            const int p = lin >> 8, c = lin & 255;
            short8 v;
            v[0]=bf16bits(f0.x); v[1]=bf16bits(f0.y); v[2]=bf16bits(f0.z); v[3]=bf16bits(f0.w);
            v[4]=bf16bits(f1.x); v[5]=bf16bits(f1.y); v[6]=bf16bits(f1.z); v[7]=bf16bits(f1.w);
            *reinterpret_cast<short8*>(&xs[p*264 + c]) = v;
        }
    }
    // stage w (bit copy with pad every 64 elems)
    {
        const uint4* wg = reinterpret_cast<const uint4*>(wdyn + (size_t)bnq * NOUT);
        #pragma unroll
        for (int i = 0; i < 8; ++i) {
            const int q = tid + 256 * i;             // uint4 (8 bf16) chunk, 2048 total
            const uint4 v = wg[q];
            const int j = q * 8;
            const int co = j >> 6, d = j & 63;
            *reinterpret_cast<uint4*>(&ws2[co*72 + d]) = v;
        }
    }
    __syncthreads();

    // grouped MFMA: mixed[p][g*64+e] = sum_d x[p][g*64+d] * w[g][e][d]
    const int mtile = wave & 1;
    floatx4 acc[2][4];
    #pragma unroll
    for (int gi = 0; gi < 2; ++gi)
        #pragma unroll
        for (int nt = 0; nt < 4; ++nt) acc[gi][nt] = (floatx4){0.f, 0.f, 0.f, 0.f};

    #pragma unroll
    for (int gi = 0; gi < 2; ++gi) {
        const int g = (wave >> 1) * 2 + gi;
        #pragma unroll
        for (int ks = 0; ks < 2; ++ks) {
            short8 a = *reinterpret_cast<const short8*>(&xs[(mtile*16 + lq)*264 + g*64 + ks*32 + quad*8]);
            #pragma unroll
            for (int nt = 0; nt < 4; ++nt) {
                short8 b = *reinterpret_cast<const short8*>(&ws2[(g*64 + nt*16 + lq)*72 + ks*32 + quad*8]);
                acc[gi][nt] = __builtin_amdgcn_mfma_f32_16x16x32_bf16(a, b, acc[gi][nt], 0, 0, 0);
            }
        }
    }

    // scatter mixed (D layout) into LDS
    #pragma unroll
    for (int gi = 0; gi < 2; ++gi) {
        const int g = (wave >> 1) * 2 + gi;
        #pragma unroll
        for (int nt = 0; nt < 4; ++nt) {
            const int c = g*64 + nt*16 + lq;
            #pragma unroll
            for (int r = 0; r < 4; ++r) {
                const int p = mtile*16 + quad*4 + r;
                ms[p*260 + c] = acc[gi][nt][r];
            }
        }
    }
    __syncthreads();

    // LayerNorm + ReLU: thread -> p = tid/8, 32 channels at (tid%8)*32
    const int p = tid >> 3, ch = tid & 7;
    const float* row = &ms[p*260 + ch*32];
    float v[32];
    float s = 0.f, ss = 0.f;
    #pragma unroll
    for (int i = 0; i < 8; ++i) {
        const float4 q = reinterpret_cast<const float4*>(row)[i];
        v[i*4+0]=q.x; v[i*4+1]=q.y; v[i*4+2]=q.z; v[i*4+3]=q.w;
        s  += q.x + q.y + q.z + q.w;
        ss += q.x*q.x + q.y*q.y + q.z*q.z + q.w*q.w;
    }
    #pragma unroll
    for (int off = 1; off < 8; off <<= 1) {
        s  += __shfl_xor(s,  off);
        ss += __shfl_xor(ss, off);
    }
    const float mu = s * (1.f/256.f);
    float var = ss * (1.f/256.f) - mu*mu;
    var = fmaxf(var, 0.f);
    const float rs = rsqrtf(var + 1e-5f);

    float* orow = out + (size_t)bnq * (32*256) + p*256 + ch*32;
    #pragma unroll
    for (int i = 0; i < 8; ++i) {
        const int c = ch*32 + i*4;
        float4 q;
        q.x = fmaxf((v[i*4+0]-mu)*rs*gs[c+0] + bs2[c+0], 0.f);
        q.y = fmaxf((v[i*4+1]-mu)*rs*gs[c+1] + bs2[c+1], 0.f);
        q.z = fmaxf((v[i*4+2]-mu)*rs*gs[c+2] + bs2[c+2], 0.f);
        q.w = fmaxf((v[i*4+3]-mu)*rs*gs[c+3] + bs2[c+3], 0.f);
        reinterpret_cast<float4*>(orow)[i] = q;
    }
}

extern "C" void kernel_launch(void* const* d_in, const int* in_sizes, int n_in,
                              void* d_out, int out_size, void* d_ws, size_t ws_size,
                              hipStream_t stream)
{
    const float* x     = (const float*)d_in[0];
    const float* qc    = (const float*)d_in[1];
    const float* Wg    = (const float*)d_in[2];
    const float* bg    = (const float*)d_in[3];
    const float* gamma = (const float*)d_in[4];
    const float* beta  = (const float*)d_in[5];
    float* out = (float*)d_out;
    __hip_bfloat16* wdyn = (__hip_bfloat16*)d_ws;   // [M, 16384] bf16 intermediate (78.6 MB)

    const int M = in_sizes[1] / HIDDEN;   // B*N = 2400

    dim3 gA(NOUT / 64, (M + 63) / 64);
    kA_gemm_w<<<gA, 256, 0, stream>>>(qc, Wg, bg, wdyn, M);
    kB_mix_ln<<<M, 256, 0, stream>>>(x, wdyn, gamma, beta, out);
}

// Round 2
// 252.260 us; speedup vs baseline: 1.0584x; 1.0584x over previous
//
#include <hip/hip_runtime.h>
#include <hip/hip_bf16.h>

typedef __attribute__((ext_vector_type(4))) float floatx4;
typedef __attribute__((ext_vector_type(8))) short short8;

#define HIDDEN 256
#define NOUT 16384   // GDIM*GDIM*GROUPS = 64*64*4

__device__ __forceinline__ short bf16bits(float x) {
    __hip_bfloat16 h = __float2bfloat16(x);
    return __builtin_bit_cast(short, h);
}

#define GLDS16(gsrc, ldst) \
    __builtin_amdgcn_global_load_lds((const __attribute__((address_space(1))) void*)(gsrc), \
                                     (__attribute__((address_space(3))) void*)(ldst), 16, 0, 0)

// ---------------- kC: fp32 -> bf16 bit convert (for qc) ----------------
__global__ __launch_bounds__(256) void kC(const float* __restrict__ src, short* __restrict__ dst, int n4)
{
    int i = blockIdx.x * 256 + threadIdx.x;
    if (i >= n4) return;
    float4 f = reinterpret_cast<const float4*>(src)[i];
    short4 v;
    v.x = bf16bits(f.x); v.y = bf16bits(f.y); v.z = bf16bits(f.z); v.w = bf16bits(f.w);
    reinterpret_cast<short4*>(dst)[i] = v;
}

// ---------------- kT: Wg[256][16384] fp32 -> WgT[16384][256] bf16 ----------------
// 64x64 tile per block, 256 threads.
__global__ __launch_bounds__(256) void kT(const float* __restrict__ Wg, short* __restrict__ WgT)
{
    __shared__ short t[64 * 68];
    const int tid = threadIdx.x;
    const int n0 = blockIdx.x * 64, k0 = blockIdx.y * 64;

    // phase 1: coalesced read along n, vector LDS write: t[kl][nl]
    const int r  = tid >> 4;        // 0..15 (k row within 16-row sweep)
    const int c4 = tid & 15;        // float4 column
    #pragma unroll
    for (int i = 0; i < 4; ++i) {
        const int kl = r + i * 16;
        float4 f = *reinterpret_cast<const float4*>(Wg + (size_t)(k0 + kl) * NOUT + n0 + c4 * 4);
        short4 v;
        v.x = bf16bits(f.x); v.y = bf16bits(f.y); v.z = bf16bits(f.z); v.w = bf16bits(f.w);
        *reinterpret_cast<short4*>(&t[kl * 68 + c4 * 4]) = v;
    }
    __syncthreads();

    // phase 2: gather 8 k's per chunk, coalesced b128 store along k
    #pragma unroll
    for (int h = 0; h < 2; ++h) {
        const int id = tid + h * 256;   // 0..511
        const int nl = id >> 3, kc = id & 7;
        short8 v;
        #pragma unroll
        for (int j = 0; j < 8; ++j) v[j] = t[(kc * 8 + j) * 68 + nl];
        *reinterpret_cast<short8*>(WgT + (size_t)(n0 + nl) * HIDDEN + k0 + kc * 8) = v;
    }
}

// ---------------- kA2: wdyn[M,16384] = bf16(qcb[M,256] @ WgT^T + bg) ----------------
// 128x128 tile, BK=32, 256 threads = 4 waves (2x2), global_load_lds staging with XOR swizzle.
__global__ __launch_bounds__(256) void kA2(
    const short* __restrict__ qcb, const short* __restrict__ WgT,
    const float* __restrict__ bg, short* __restrict__ wdyn, int M)
{
    __shared__ short As[128 * 32];
    __shared__ short Bs[128 * 32];

    const int tid  = threadIdx.x;
    const int wave = tid >> 6, lane = tid & 63;
    const int lq   = lane & 15, quad = lane >> 4;
    const int wm   = wave >> 1, wn = wave & 1;
    const int m0   = blockIdx.y * 128;
    const int n0   = blockIdx.x * 128;

    // staging: lane -> row chunk. ml = row within 16-row group, kq = swizzled k-chunk (8 bf16)
    const int ml = lane >> 2;
    const int kq = (lane & 3) ^ ((lane >> 3) & 3);

    // global source pointers (advance 32 elems per K-step)
    int rowA0 = m0 + wave * 32 + ml;       if (rowA0 >= M) rowA0 = M - 1;
    int rowA1 = m0 + wave * 32 + 16 + ml;  if (rowA1 >= M) rowA1 = M - 1;
    const int rowB0 = n0 + wave * 32 + ml;
    const int rowB1 = rowB0 + 16;
    const short* aSrc0 = qcb + (size_t)rowA0 * HIDDEN + kq * 8;
    const short* aSrc1 = qcb + (size_t)rowA1 * HIDDEN + kq * 8;
    const short* bSrc0 = WgT + (size_t)rowB0 * HIDDEN + kq * 8;
    const short* bSrc1 = WgT + (size_t)rowB1 * HIDDEN + kq * 8;
    short* aDst0 = &As[(wave * 32) * 32];
    short* aDst1 = &As[(wave * 32 + 16) * 32];
    short* bDst0 = &Bs[(wave * 32) * 32];
    short* bDst1 = &Bs[(wave * 32 + 16) * 32];

    // fragment read addresses (constant across K-steps; swizzled chunk)
    const int kswz = quad ^ ((lq >> 1) & 3);
    const short* aFrag[4];
    const short* bFrag[4];
    #pragma unroll
    for (int i = 0; i < 4; ++i) {
        aFrag[i] = &As[(wm * 64 + i * 16 + lq) * 32 + kswz * 8];
        bFrag[i] = &Bs[(wn * 64 + i * 16 + lq) * 32 + kswz * 8];
    }

    floatx4 acc[4][4];
    #pragma unroll
    for (int i = 0; i < 4; ++i)
        #pragma unroll
        for (int j = 0; j < 4; ++j) acc[i][j] = (floatx4){0.f, 0.f, 0.f, 0.f};

    for (int k0 = 0; k0 < HIDDEN; k0 += 32) {
        GLDS16(aSrc0, aDst0);
        GLDS16(aSrc1, aDst1);
        GLDS16(bSrc0, bDst0);
        GLDS16(bSrc1, bDst1);
        aSrc0 += 32; aSrc1 += 32; bSrc0 += 32; bSrc1 += 32;
        __syncthreads();

        short8 a[4], b[4];
        #pragma unroll
        for (int i = 0; i < 4; ++i) a[i] = *reinterpret_cast<const short8*>(aFrag[i]);
        #pragma unroll
        for (int j = 0; j < 4; ++j) b[j] = *reinterpret_cast<const short8*>(bFrag[j]);
        #pragma unroll
        for (int i = 0; i < 4; ++i)
            #pragma unroll
            for (int j = 0; j < 4; ++j)
                acc[i][j] = __builtin_amdgcn_mfma_f32_16x16x32_bf16(a[i], b[j], acc[i][j], 0, 0, 0);
        __syncthreads();
    }

    // epilogue: D layout col=lane&15, row=quad*4+r
    #pragma unroll
    for (int j = 0; j < 4; ++j) {
        const int col = n0 + wn * 64 + j * 16 + lq;
        const float bv = bg[col];
        #pragma unroll
        for (int i = 0; i < 4; ++i) {
            const int rbase = m0 + wm * 64 + i * 16 + quad * 4;
            #pragma unroll
            for (int r = 0; r < 4; ++r) {
                const int row = rbase + r;
                if (row < M) wdyn[(size_t)row * NOUT + col] = bf16bits(acc[i][j][r] + bv);
            }
        }
    }
}

// ---------------- kB2: per (b,n): grouped mix + in-register LayerNorm + ReLU ----------------
// 256 threads = 4 waves: mtile = wave&1 (16 p-rows), gp = wave>>1 (2 groups). No big LDS.
__global__ __launch_bounds__(256) void kB2(
    const float* __restrict__ x, const short* __restrict__ wdyn,
    const float* __restrict__ gamma, const float* __restrict__ beta,
    float* __restrict__ out)
{
    __shared__ float red[2][4][4][2][2];   // [mtile][quad][r][gp][s/ss] = 512 B

    const int tid  = threadIdx.x;
    const int bnq  = blockIdx.x;
    const int wave = tid >> 6, lane = tid & 63;
    const int lq   = lane & 15, quad = lane >> 4;
    const int mtile = wave & 1, gp = wave >> 1;

    const float* xr = x + (size_t)bnq * (32 * HIDDEN) + (mtile * 16 + lq) * HIDDEN;
    const short* wr = wdyn + (size_t)bnq * NOUT;

    // a-frags: x row p = mtile*16+lq, channels g*64 + ks*32 + quad*8 .. +7 (fp32 -> bf16)
    short8 afr[2][2];
    #pragma unroll
    for (int gi = 0; gi < 2; ++gi) {
        const int g = gp * 2 + gi;
        #pragma unroll
        for (int ks = 0; ks < 2; ++ks) {
            const float4* s = reinterpret_cast<const float4*>(xr + g * 64 + ks * 32 + quad * 8);
            const float4 f0 = s[0], f1 = s[1];
            short8 v;
            v[0]=bf16bits(f0.x); v[1]=bf16bits(f0.y); v[2]=bf16bits(f0.z); v[3]=bf16bits(f0.w);
            v[4]=bf16bits(f1.x); v[5]=bf16bits(f1.y); v[6]=bf16bits(f1.z); v[7]=bf16bits(f1.w);
            afr[gi][ks] = v;
        }
    }

    // b-frags straight from global (wdyn row = B-operand layout), MFMA accumulate
    floatx4 acc[2][4];
    #pragma unroll
    for (int gi = 0; gi < 2; ++gi)
        #pragma unroll
        for (int nt = 0; nt < 4; ++nt) acc[gi][nt] = (floatx4){0.f, 0.f, 0.f, 0.f};

    #pragma unroll
    for (int gi = 0; gi < 2; ++gi) {
        const int g = gp * 2 + gi;
        #pragma unroll
        for (int ks = 0; ks < 2; ++ks) {
            #pragma unroll
            for (int nt = 0; nt < 4; ++nt) {
                const short8 b = *reinterpret_cast<const short8*>(
                    wr + (g * 64 + nt * 16 + lq) * 64 + ks * 32 + quad * 8);
                acc[gi][nt] = __builtin_amdgcn_mfma_f32_16x16x32_bf16(afr[gi][ks], b, acc[gi][nt], 0, 0, 0);
            }
        }
    }

    // in-register LN reduction: per lane, per r: sum over its 8 channels
    float s[4], ss[4];
    #pragma unroll
    for (int r = 0; r < 4; ++r) { s[r] = 0.f; ss[r] = 0.f; }
    #pragma unroll
    for (int gi = 0; gi < 2; ++gi)
        #pragma unroll
        for (int nt = 0; nt < 4; ++nt)
            #pragma unroll
            for (int r = 0; r < 4; ++r) {
                const float v = acc[gi][nt][r];
                s[r] += v; ss[r] += v * v;
            }
    // reduce across the 16 lanes of the quad (same p rows)
    #pragma unroll
    for (int off = 1; off < 16; off <<= 1) {
        #pragma unroll
        for (int r = 0; r < 4; ++r) {
            s[r]  += __shfl_xor(s[r],  off);
            ss[r] += __shfl_xor(ss[r], off);
        }
    }
    if (lq == 0) {
        #pragma unroll
        for (int r = 0; r < 4; ++r) {
            red[mtile][quad][r][gp][0] = s[r];
            red[mtile][quad][r][gp][1] = ss[r];
        }
    }
    __syncthreads();

    float mu[4], rs[4];
    #pragma unroll
    for (int r = 0; r < 4; ++r) {
        const float S  = s[r]  + red[mtile][quad][r][gp ^ 1][0];
        const float SS = ss[r] + red[mtile][quad][r][gp ^ 1][1];
        mu[r] = S * (1.f / 256.f);
        float var = SS * (1.f / 256.f) - mu[r] * mu[r];
        var = fmaxf(var, 0.f);
        rs[r] = rsqrtf(var + 1e-5f);
    }

    // normalize + affine + relu, write straight to global
    float* orow = out + (size_t)bnq * (32 * HIDDEN);
    #pragma unroll
    for (int gi = 0; gi < 2; ++gi) {
        const int g = gp * 2 + gi;
        #pragma unroll
        for (int nt = 0; nt < 4; ++nt) {
            const int c = g * 64 + nt * 16 + lq;
            const float gm = gamma[c], bt = beta[c];
            #pragma unroll
            for (int r = 0; r < 4; ++r) {
                const int p = mtile * 16 + quad * 4 + r;
                const float v = fmaxf((acc[gi][nt][r] - mu[r]) * rs[r] * gm + bt, 0.f);
                orow[p * HIDDEN + c] = v;
            }
        }
    }
}

extern "C" void kernel_launch(void* const* d_in, const int* in_sizes, int n_in,
                              void* d_out, int out_size, void* d_ws, size_t ws_size,
                              hipStream_t stream)
{
    const float* x     = (const float*)d_in[0];
    const float* qc    = (const float*)d_in[1];
    const float* Wg    = (const float*)d_in[2];
    const float* bg    = (const float*)d_in[3];
    const float* gamma = (const float*)d_in[4];
    const float* beta  = (const float*)d_in[5];
    float* out = (float*)d_out;

    const int M = in_sizes[1] / HIDDEN;   // B*N = 2400

    // workspace layout (bytes)
    char* ws = (char*)d_ws;
    short* wdyn = (short*)ws;                                   // M*16384*2      = 78,643,200
    short* WgT  = (short*)(ws + (size_t)M * NOUT * 2);          // 16384*256*2    =  8,388,608
    short* qcb  = (short*)(ws + (size_t)M * NOUT * 2 + (size_t)NOUT * HIDDEN * 2); // M*256*2

    // 1) qc -> bf16
    {
        const int n4 = (M * HIDDEN) / 4;
        kC<<<(n4 + 255) / 256, 256, 0, stream>>>(qc, qcb, n4);
    }
    // 2) Wg -> WgT (bf16, transposed)
    kT<<<dim3(NOUT / 64, HIDDEN / 64), 256, 0, stream>>>(Wg, WgT);
    // 3) dynamic-weight GEMM
    kA2<<<dim3(NOUT / 128, (M + 127) / 128), 256, 0, stream>>>(qcb, WgT, bg, wdyn, M);
    // 4) grouped mixing + LN + ReLU
    kB2<<<M, 256, 0, stream>>>(x, wdyn, gamma, beta, out);
}

// Round 4
// 237.612 us; speedup vs baseline: 1.1237x; 1.0616x over previous
//
#include <hip/hip_runtime.h>
#include <hip/hip_bf16.h>

typedef __attribute__((ext_vector_type(4))) float floatx4;
typedef __attribute__((ext_vector_type(8))) short short8;

#define HIDDEN 256
#define NOUT 16384   // GDIM*GDIM*GROUPS = 64*64*4

static __device__ __forceinline__ short bf16bits(float x) {
    __hip_bfloat16 h = __float2bfloat16(x);
    return __builtin_bit_cast(short, h);
}

#define GLDS16(gsrc, ldst) \
    __builtin_amdgcn_global_load_lds((const __attribute__((address_space(1))) void*)(gsrc), \
                                     (__attribute__((address_space(3))) void*)(ldst), 16, 0, 0)

// ---------------- kPrep: [blocks 0..1023] Wg fp32 -> WgT bf16 transposed; [rest] qc -> bf16 ----------------
__global__ __launch_bounds__(256) void kPrep(
    const float* __restrict__ Wg, short* __restrict__ WgT,
    const float* __restrict__ qc, short* __restrict__ qcb, int n4)
{
    __shared__ short t[64 * 68];
    const int tid = threadIdx.x;

    if (blockIdx.x < 1024) {
        const int n0 = (blockIdx.x & 255) * 64, k0 = (blockIdx.x >> 8) * 64;
        // phase 1: coalesced read along n, write t[kl][nl] (bf16)
        const int r  = tid >> 4;
        const int c4 = tid & 15;
        #pragma unroll
        for (int i = 0; i < 4; ++i) {
            const int kl = r + i * 16;
            float4 f = *reinterpret_cast<const float4*>(Wg + (size_t)(k0 + kl) * NOUT + n0 + c4 * 4);
            short4 v;
            v.x = bf16bits(f.x); v.y = bf16bits(f.y); v.z = bf16bits(f.z); v.w = bf16bits(f.w);
            *reinterpret_cast<short4*>(&t[kl * 68 + c4 * 4]) = v;
        }
        __syncthreads();
        // phase 2: gather k-contiguous, coalesced b128 store
        #pragma unroll
        for (int h = 0; h < 2; ++h) {
            const int id = tid + h * 256;
            const int nl = id >> 3, kc = id & 7;
            short8 v;
            #pragma unroll
            for (int j = 0; j < 8; ++j) v[j] = t[(kc * 8 + j) * 68 + nl];
            *reinterpret_cast<short8*>(WgT + (size_t)(n0 + nl) * HIDDEN + k0 + kc * 8) = v;
        }
    } else {
        const int i = (blockIdx.x - 1024) * 256 + tid;
        if (i < n4) {
            float4 f = reinterpret_cast<const float4*>(qc)[i];
            short4 v;
            v.x = bf16bits(f.x); v.y = bf16bits(f.y); v.z = bf16bits(f.z); v.w = bf16bits(f.w);
            reinterpret_cast<short4*>(qcb)[i] = v;
        }
    }
}

// ---------------- kA3: wdyn[M,16384] = bf16(qcb[M,256] @ WgT^T + bg) ----------------
// 128x128 tile, BK=64, 256 threads = 4 waves (2x2). global_load_lds with source-side XOR swizzle.
// LDS-restaged epilogue for coalesced bf16 stores.
__global__ __launch_bounds__(256) void kA3(
    const short* __restrict__ qcb, const short* __restrict__ WgT,
    const float* __restrict__ bg, short* __restrict__ wdyn, int M)
{
    __shared__ short As[128 * 64];   // 16 KB, [row][k-chunk^swz]
    __shared__ short Bs[128 * 64];   // 16 KB

    const int tid  = threadIdx.x;
    const int wave = tid >> 6, lane = tid & 63;
    const int lq   = lane & 15, quad = lane >> 4;
    const int wm   = wave >> 1, wn = wave & 1;
    const int m0   = blockIdx.x * 128;
    const int n0   = blockIdx.y * 128;

    // staging: 1024 16B-chunks per buffer per iter; 4 GLDS per thread per buffer.
    // LDS slot (row, c) holds global k-chunk (c ^ (row&7)) -> source carries the swizzle.
    const short* aSrc[4]; const short* bSrc[4];
    short* aDst[4]; short* bDst[4];
    #pragma unroll
    for (int t = 0; t < 4; ++t) {
        const int chunk = t * 256 + wave * 64 + lane;
        const int row = chunk >> 3, kc = chunk & 7;
        const int kcs = kc ^ (row & 7);
        int rA = m0 + row; if (rA >= M) rA = M - 1;
        aSrc[t] = qcb + (size_t)rA * HIDDEN + kcs * 8;
        bSrc[t] = WgT + (size_t)(n0 + row) * HIDDEN + kcs * 8;
        aDst[t] = &As[(t * 256 + wave * 64) * 8];   // wave-uniform; HW adds lane*16B
        bDst[t] = &Bs[(t * 256 + wave * 64) * 8];
    }

    // fragment LDS offsets (shorts), constant across iters
    int aOff[2][4], bOff[2][4];
    #pragma unroll
    for (int ks = 0; ks < 2; ++ks)
        #pragma unroll
        for (int i = 0; i < 4; ++i) {
            const int ra = wm * 64 + i * 16 + lq;
            aOff[ks][i] = ra * 64 + (((ks * 4 + quad) ^ (ra & 7)) * 8);
            const int rb = wn * 64 + i * 16 + lq;
            bOff[ks][i] = rb * 64 + (((ks * 4 + quad) ^ (rb & 7)) * 8);
        }

    floatx4 acc[4][4];
    #pragma unroll
    for (int i = 0; i < 4; ++i)
        #pragma unroll
        for (int j = 0; j < 4; ++j) acc[i][j] = (floatx4){0.f, 0.f, 0.f, 0.f};

    for (int it = 0; it < 4; ++it) {
        #pragma unroll
        for (int t = 0; t < 4; ++t) {
            GLDS16(aSrc[t], aDst[t]);
            GLDS16(bSrc[t], bDst[t]);
            aSrc[t] += 64; bSrc[t] += 64;
        }
        __syncthreads();

        #pragma unroll
        for (int ks = 0; ks < 2; ++ks) {
            short8 a[4], b[4];
            #pragma unroll
            for (int i = 0; i < 4; ++i) a[i] = *reinterpret_cast<const short8*>(&As[aOff[ks][i]]);
            #pragma unroll
            for (int j = 0; j < 4; ++j) b[j] = *reinterpret_cast<const short8*>(&Bs[bOff[ks][j]]);
            #pragma unroll
            for (int i = 0; i < 4; ++i)
                #pragma unroll
                for (int j = 0; j < 4; ++j)
                    acc[i][j] = __builtin_amdgcn_mfma_f32_16x16x32_bf16(a[i], b[j], acc[i][j], 0, 0, 0);
        }
        __syncthreads();
    }

    // epilogue: bias add, restage through LDS (reuse As as 64x128 bf16), coalesced stores
    float bv[4];
    #pragma unroll
    for (int j = 0; j < 4; ++j) bv[j] = bg[n0 + wn * 64 + j * 16 + lq];

    short* Cs = As;
    #pragma unroll
    for (int half = 0; half < 2; ++half) {
        if (half) __syncthreads();
        if (wm == half) {
            #pragma unroll
            for (int j = 0; j < 4; ++j)
                #pragma unroll
                for (int i = 0; i < 4; ++i)
                    #pragma unroll
                    for (int r = 0; r < 4; ++r)
                        Cs[(i * 16 + quad * 4 + r) * 128 + wn * 64 + j * 16 + lq] =
                            bf16bits(acc[i][j][r] + bv[j]);
        }
        __syncthreads();
        #pragma unroll
        for (int t = 0; t < 4; ++t) {
            const int id = t * 256 + tid;
            const int mr = id >> 4, ch = id & 15;
            const int grow = m0 + half * 64 + mr;
            if (grow < M)
                *reinterpret_cast<short8*>(&wdyn[(size_t)grow * NOUT + n0 + ch * 8]) =
                    *reinterpret_cast<const short8*>(&Cs[mr * 128 + ch * 8]);
        }
    }
}

// ---------------- kB3: per (b,n): grouped mix + in-register LayerNorm + ReLU ----------------
__global__ __launch_bounds__(256) void kB3(
    const float* __restrict__ x, const short* __restrict__ wdyn,
    const float* __restrict__ gamma, const float* __restrict__ beta,
    float* __restrict__ out)
{
    __shared__ float red[2][4][4][2][2];   // [mtile][quad][r][gp][s/ss] = 512 B

    const int tid  = threadIdx.x;
    const int bnq  = blockIdx.x;
    const int wave = tid >> 6, lane = tid & 63;
    const int lq   = lane & 15, quad = lane >> 4;
    const int mtile = wave & 1, gp = wave >> 1;

    const float* xr = x + (size_t)bnq * (32 * HIDDEN) + (mtile * 16 + lq) * HIDDEN;
    const short* wr = wdyn + (size_t)bnq * NOUT;

    // a-frags: x row, fp32 -> bf16 (nontemporal: streamed once)
    short8 afr[2][2];
    #pragma unroll
    for (int gi = 0; gi < 2; ++gi) {
        const int g = gp * 2 + gi;
        #pragma unroll
        for (int ks = 0; ks < 2; ++ks) {
            const floatx4* s = reinterpret_cast<const floatx4*>(xr + g * 64 + ks * 32 + quad * 8);
            const floatx4 f0 = __builtin_nontemporal_load(s);
            const floatx4 f1 = __builtin_nontemporal_load(s + 1);
            short8 v;
            v[0]=bf16bits(f0[0]); v[1]=bf16bits(f0[1]); v[2]=bf16bits(f0[2]); v[3]=bf16bits(f0[3]);
            v[4]=bf16bits(f1[0]); v[5]=bf16bits(f1[1]); v[6]=bf16bits(f1[2]); v[7]=bf16bits(f1[3]);
            afr[gi][ks] = v;
        }
    }

    floatx4 acc[2][4];
    #pragma unroll
    for (int gi = 0; gi < 2; ++gi)
        #pragma unroll
        for (int nt = 0; nt < 4; ++nt) acc[gi][nt] = (floatx4){0.f, 0.f, 0.f, 0.f};

    #pragma unroll
    for (int gi = 0; gi < 2; ++gi) {
        const int g = gp * 2 + gi;
        #pragma unroll
        for (int ks = 0; ks < 2; ++ks) {
            #pragma unroll
            for (int nt = 0; nt < 4; ++nt) {
                const short8 b = __builtin_nontemporal_load(reinterpret_cast<const short8*>(
                    wr + (g * 64 + nt * 16 + lq) * 64 + ks * 32 + quad * 8));
                acc[gi][nt] = __builtin_amdgcn_mfma_f32_16x16x32_bf16(afr[gi][ks], b, acc[gi][nt], 0, 0, 0);
            }
        }
    }

    // in-register LN reduction
    float s[4], ss[4];
    #pragma unroll
    for (int r = 0; r < 4; ++r) { s[r] = 0.f; ss[r] = 0.f; }
    #pragma unroll
    for (int gi = 0; gi < 2; ++gi)
        #pragma unroll
        for (int nt = 0; nt < 4; ++nt)
            #pragma unroll
            for (int r = 0; r < 4; ++r) {
                const float v = acc[gi][nt][r];
                s[r] += v; ss[r] += v * v;
            }
    #pragma unroll
    for (int off = 1; off < 16; off <<= 1) {
        #pragma unroll
        for (int r = 0; r < 4; ++r) {
            s[r]  += __shfl_xor(s[r],  off);
            ss[r] += __shfl_xor(ss[r], off);
        }
    }
    if (lq == 0) {
        #pragma unroll
        for (int r = 0; r < 4; ++r) {
            red[mtile][quad][r][gp][0] = s[r];
            red[mtile][quad][r][gp][1] = ss[r];
        }
    }
    __syncthreads();

    float mu[4], rs[4];
    #pragma unroll
    for (int r = 0; r < 4; ++r) {
        const float S  = s[r]  + red[mtile][quad][r][gp ^ 1][0];
        const float SS = ss[r] + red[mtile][quad][r][gp ^ 1][1];
        mu[r] = S * (1.f / 256.f);
        float var = SS * (1.f / 256.f) - mu[r] * mu[r];
        var = fmaxf(var, 0.f);
        rs[r] = rsqrtf(var + 1e-5f);
    }

    // normalize + affine + relu, nontemporal stores
    float* orow = out + (size_t)bnq * (32 * HIDDEN);
    #pragma unroll
    for (int gi = 0; gi < 2; ++gi) {
        const int g = gp * 2 + gi;
        #pragma unroll
        for (int nt = 0; nt < 4; ++nt) {
            const int c = g * 64 + nt * 16 + lq;
            const float gm = gamma[c], bt = beta[c];
            #pragma unroll
            for (int r = 0; r < 4; ++r) {
                const int p = mtile * 16 + quad * 4 + r;
                const float v = fmaxf((acc[gi][nt][r] - mu[r]) * rs[r] * gm + bt, 0.f);
                __builtin_nontemporal_store(v, &orow[p * HIDDEN + c]);
            }
        }
    }
}

extern "C" void kernel_launch(void* const* d_in, const int* in_sizes, int n_in,
                              void* d_out, int out_size, void* d_ws, size_t ws_size,
                              hipStream_t stream)
{
    const float* x     = (const float*)d_in[0];
    const float* qc    = (const float*)d_in[1];
    const float* Wg    = (const float*)d_in[2];
    const float* bg    = (const float*)d_in[3];
    const float* gamma = (const float*)d_in[4];
    const float* beta  = (const float*)d_in[5];
    float* out = (float*)d_out;

    const int M = in_sizes[1] / HIDDEN;   // B*N = 2400

    // workspace layout (bytes)
    char* ws = (char*)d_ws;
    short* wdyn = (short*)ws;                                    // M*16384*2
    short* WgT  = (short*)(ws + (size_t)M * NOUT * 2);           // 16384*256*2
    short* qcb  = (short*)(ws + (size_t)M * NOUT * 2 + (size_t)NOUT * HIDDEN * 2);

    const int n4 = (M * HIDDEN) / 4;
    const int prepBlocks = 1024 + (n4 + 255) / 256;
    kPrep<<<prepBlocks, 256, 0, stream>>>(Wg, WgT, qc, qcb, n4);

    kA3<<<dim3((M + 127) / 128, NOUT / 128), 256, 0, stream>>>(qcb, WgT, bg, wdyn, M);

    kB3<<<M, 256, 0, stream>>>(x, wdyn, gamma, beta, out);
}